// Round 1
// baseline (2547.949 us; speedup 1.0000x reference)
//
#include <hip/hip_runtime.h>
#include <hip/hip_bf16.h>
#include <math.h>

// Problem constants
#define S_LEN 2048
#define HID   2048
#define NHEAD 16
#define NKVH  4
#define HDIM  128
#define FFDIM 8192

typedef __bf16 bf16x8 __attribute__((ext_vector_type(8)));
typedef float  f32x4  __attribute__((ext_vector_type(4)));

__device__ __forceinline__ unsigned short f2b(float x) {
  __hip_bfloat16 h = __float2bfloat16(x);
  return __builtin_bit_cast(unsigned short, h);
}

__device__ __forceinline__ float block_sum_256(float v) {
  __shared__ float red[4];
  #pragma unroll
  for (int o = 32; o > 0; o >>= 1) v += __shfl_down(v, o, 64);
  if ((threadIdx.x & 63) == 0) red[threadIdx.x >> 6] = v;
  __syncthreads();
  v = red[0] + red[1] + red[2] + red[3];
  __syncthreads();
  return v;
}

__device__ __forceinline__ float block_max_256(float v) {
  __shared__ float redm[4];
  #pragma unroll
  for (int o = 32; o > 0; o >>= 1) v = fmaxf(v, __shfl_down(v, o, 64));
  if ((threadIdx.x & 63) == 0) redm[threadIdx.x >> 6] = v;
  __syncthreads();
  v = fmaxf(fmaxf(redm[0], redm[1]), fmaxf(redm[2], redm[3]));
  __syncthreads();
  return v;
}

// ---------------- embedding ----------------
__global__ __launch_bounds__(256) void embed_kernel(
    const int* __restrict__ ids, const float* __restrict__ vemb,
    const float* __restrict__ aemb, float* __restrict__ h, int* __restrict__ amask) {
  const int s = blockIdx.x;
  const int id = ids[s];
  const bool am = id > 31999;
  if (threadIdx.x == 0) amask[s] = am ? 1 : 0;
  const int d0 = threadIdx.x * 8;
  float out[8];
  if (am) {
    const int at = id - 32000;
    #pragma unroll
    for (int u = 0; u < 8; u++) out[u] = 0.f;
    for (int cb = 0; cb < 8; cb++) {
      const float* src = aemb + (long)(at + cb * 1024) * HID + d0;
      #pragma unroll
      for (int u = 0; u < 8; u++) out[u] += src[u];
    }
  } else {
    const float* src = vemb + (long)id * HID + d0;
    #pragma unroll
    for (int u = 0; u < 8; u++) out[u] = src[u];
  }
  float* dst = h + (long)s * HID + d0;
  #pragma unroll
  for (int u = 0; u < 8; u++) dst[u] = out[u];
}

// ---------------- weight transpose + f32->bf16 ----------------
// W is K x N (row stride ldw); writes Wt = W^T as N x K bf16.
__global__ __launch_bounds__(256) void transposew(
    const float* __restrict__ W, int ldw, unsigned short* __restrict__ Wt, int K, int N) {
  __shared__ float t[32][33];
  const int k0 = blockIdx.y * 32, n0 = blockIdx.x * 32;
  const int tx = threadIdx.x & 31, ty = threadIdx.x >> 5;  // 32 x 8
  #pragma unroll
  for (int i = 0; i < 4; i++)
    t[ty + i * 8][tx] = W[(long)(k0 + ty + i * 8) * ldw + n0 + tx];
  __syncthreads();
  #pragma unroll
  for (int i = 0; i < 4; i++)
    Wt[(long)(n0 + ty + i * 8) * K + k0 + tx] = f2b(t[tx][ty + i * 8]);
}

// ---------------- RoPE ----------------
__global__ __launch_bounds__(256) void rope_table(float* __restrict__ c, float* __restrict__ s_) {
  const int i = blockIdx.x * 256 + threadIdx.x;  // S_LEN*64 total
  const int pos = i >> 6, j = i & 63;
  const float inv = powf(10000.f, -(float)(2 * j) * (1.f / 128.f));
  const float ang = (float)pos * inv;
  c[i] = cosf(ang);
  s_[i] = sinf(ang);
}

// qkv: [S][3072] f32 (q|k|v). Writes qb [S][2048] bf16, kb [S][512] bf16 (rope applied).
__global__ __launch_bounds__(64) void rope_apply(
    const float* __restrict__ qkv, const float* __restrict__ rc, const float* __restrict__ rs,
    unsigned short* __restrict__ qb, unsigned short* __restrict__ kb) {
  const int s = blockIdx.x;
  const int hh = blockIdx.y;  // 0..15 q heads, 16..19 kv heads
  const int j = threadIdx.x;  // 0..63
  const float c = rc[s * 64 + j], sn = rs[s * 64 + j];
  const float* base;
  unsigned short* out;
  if (hh < 16) {
    base = qkv + (long)s * 3072 + hh * 128;
    out = qb + (long)s * 2048 + hh * 128;
  } else {
    base = qkv + (long)s * 3072 + 2048 + (hh - 16) * 128;
    out = kb + (long)s * 512 + (hh - 16) * 128;
  }
  const float x1 = base[j], x2 = base[j + 64];
  out[j] = f2b(x1 * c - x2 * sn);
  out[j + 64] = f2b(x2 * c + x1 * sn);
}

// ---------------- RMSNorms ----------------
__global__ __launch_bounds__(256) void rmsnorm_sel(
    const float* __restrict__ x, const int* __restrict__ amask,
    const float* __restrict__ wt, const float* __restrict__ wa, unsigned short* __restrict__ out) {
  const long s = blockIdx.x;
  const float* xr = x + s * HID;
  const int d0 = threadIdx.x * 8;
  float v[8], ss = 0.f;
  #pragma unroll
  for (int u = 0; u < 8; u++) { v[u] = xr[d0 + u]; ss += v[u] * v[u]; }
  ss = block_sum_256(ss) * (1.f / HID);
  const float rr = rsqrtf(ss + 1e-5f);
  const float* w = amask[s] ? wa : wt;
  #pragma unroll
  for (int u = 0; u < 8; u++) out[s * HID + d0 + u] = f2b(v[u] * rr * w[d0 + u]);
}

__global__ __launch_bounds__(256) void rmsnorm_dual(
    const float* __restrict__ x, const float* __restrict__ wt, const float* __restrict__ wa,
    unsigned short* __restrict__ ot, unsigned short* __restrict__ oa) {
  const long s = blockIdx.x;
  const float* xr = x + s * HID;
  const int d0 = threadIdx.x * 8;
  float v[8], ss = 0.f;
  #pragma unroll
  for (int u = 0; u < 8; u++) { v[u] = xr[d0 + u]; ss += v[u] * v[u]; }
  ss = block_sum_256(ss) * (1.f / HID);
  const float rr = rsqrtf(ss + 1e-5f);
  #pragma unroll
  for (int u = 0; u < 8; u++) {
    const float xn = v[u] * rr;
    ot[s * HID + d0 + u] = f2b(xn * wt[d0 + u]);
    oa[s * HID + d0 + u] = f2b(xn * wa[d0 + u]);
  }
}

__global__ __launch_bounds__(256) void rmsnorm_final(
    const float* __restrict__ x, const float* __restrict__ w, float* __restrict__ out) {
  const long s = blockIdx.x;
  const float* xr = x + s * HID;
  const int d0 = threadIdx.x * 8;
  float v[8], ss = 0.f;
  #pragma unroll
  for (int u = 0; u < 8; u++) { v[u] = xr[d0 + u]; ss += v[u] * v[u]; }
  ss = block_sum_256(ss) * (1.f / HID);
  const float rr = rsqrtf(ss + 1e-5f);
  #pragma unroll
  for (int u = 0; u < 8; u++) out[s * HID + d0 + u] = v[u] * rr * w[d0 + u];
}

// ---------------- softmax over score rows ----------------
__global__ __launch_bounds__(256) void softmax_rows(
    const float* __restrict__ Sc, unsigned short* __restrict__ P) {
  const long row = blockIdx.x;
  const float* x = Sc + row * S_LEN;
  unsigned short* p = P + row * S_LEN;
  const int d0 = threadIdx.x * 8;
  float v[8], m = -1e30f;
  #pragma unroll
  for (int u = 0; u < 8; u++) { v[u] = x[d0 + u]; m = fmaxf(m, v[u]); }
  m = block_max_256(m);
  float sum = 0.f;
  #pragma unroll
  for (int u = 0; u < 8; u++) { v[u] = expf(v[u] - m); sum += v[u]; }
  sum = block_sum_256(sum);
  const float inv = 1.f / sum;
  #pragma unroll
  for (int u = 0; u < 8; u++) p[d0 + u] = f2b(v[u] * inv);
}

// ---------------- bf16 MFMA GEMM, C = A @ Bt^T ----------------
// A: M x K bf16 (row stride lda), Bt: N x K bf16 (row stride ldb).
// 128x128 tile, BK=32, 4 waves, global_load_lds(16B) staging.
// EPI: 0 f32 store | 1 scale+causal->f32 | 2 silu->bf16 | 3 f32 += | 4 bf16 store
//      5 f32 += (mask ? acc : aux)
#define BM 128
#define BN 128
#define BKK 32

__device__ __forceinline__ void gload16(const void* g, void* l) {
  __builtin_amdgcn_global_load_lds((const __attribute__((address_space(1))) void*)g,
                                   (__attribute__((address_space(3))) void*)l, 16, 0, 0);
}

template <int EPI>
__global__ __launch_bounds__(256) void gemm_bt(
    const unsigned short* __restrict__ A, int lda, long sAz,
    const unsigned short* __restrict__ Bt, int ldb, long sBz,
    void* __restrict__ Cv, int ldc, long sCz, int K, float scale,
    const float* __restrict__ aux, const int* __restrict__ mask) {
  __shared__ __align__(16) unsigned short smA[BM * BKK];
  __shared__ __align__(16) unsigned short smB[BN * BKK];
  const int tid = threadIdx.x;
  const int lane = tid & 63;
  const int wave = tid >> 6;
  const int bm = blockIdx.y * BM;
  const int bn = blockIdx.x * BN;
  const int z = blockIdx.z;
  A += sAz * z;
  Bt += sBz * z;
  const int wm = (wave >> 1) * 64;
  const int wn = (wave & 1) * 64;
  const int lr = lane & 15;
  const int lk = (lane >> 4) * 8;

  f32x4 acc[4][4];
  #pragma unroll
  for (int i = 0; i < 4; i++)
    #pragma unroll
    for (int j = 0; j < 4; j++) acc[i][j] = (f32x4){0.f, 0.f, 0.f, 0.f};

  const int c0 = tid, c1 = tid + 256;
  const long arow0 = (long)(bm + (c0 >> 2)) * lda + (c0 & 3) * 8;
  const long arow1 = (long)(bm + (c1 >> 2)) * lda + (c1 & 3) * 8;
  const long brow0 = (long)(bn + (c0 >> 2)) * ldb + (c0 & 3) * 8;
  const long brow1 = (long)(bn + (c1 >> 2)) * ldb + (c1 & 3) * 8;

  for (int k0 = 0; k0 < K; k0 += BKK) {
    gload16(A + arow0 + k0, smA + c0 * 8);
    gload16(A + arow1 + k0, smA + c1 * 8);
    gload16(Bt + brow0 + k0, smB + c0 * 8);
    gload16(Bt + brow1 + k0, smB + c1 * 8);
    asm volatile("s_waitcnt vmcnt(0)" ::: "memory");
    __syncthreads();
    bf16x8 af[4], bfv[4];
    #pragma unroll
    for (int i = 0; i < 4; i++) af[i] = *(const bf16x8*)(smA + (wm + i * 16 + lr) * BKK + lk);
    #pragma unroll
    for (int j = 0; j < 4; j++) bfv[j] = *(const bf16x8*)(smB + (wn + j * 16 + lr) * BKK + lk);
    #pragma unroll
    for (int i = 0; i < 4; i++)
      #pragma unroll
      for (int j = 0; j < 4; j++)
        acc[i][j] = __builtin_amdgcn_mfma_f32_16x16x32_bf16(af[i], bfv[j], acc[i][j], 0, 0, 0);
    __syncthreads();
  }

  const int r0 = bm + wm + (lane >> 4) * 4;
  const int cb = bn + wn + lr;
  #pragma unroll
  for (int i = 0; i < 4; i++) {
    #pragma unroll
    for (int j = 0; j < 4; j++) {
      #pragma unroll
      for (int r = 0; r < 4; r++) {
        const int grow = r0 + i * 16 + r;
        const int gcol = cb + j * 16;
        const long idx = (long)grow * ldc + gcol;
        float v = acc[i][j][r];
        if constexpr (EPI == 0) {
          ((float*)Cv)[sCz * z + idx] = v;
        } else if constexpr (EPI == 1) {
          v *= scale;
          if (gcol > grow) v = -1e9f;
          ((float*)Cv)[sCz * z + idx] = v;
        } else if constexpr (EPI == 2) {
          const float sl = v / (1.f + expf(-v));
          ((unsigned short*)Cv)[sCz * z + idx] = f2b(sl);
        } else if constexpr (EPI == 3) {
          ((float*)Cv)[sCz * z + idx] += v;
        } else if constexpr (EPI == 4) {
          ((unsigned short*)Cv)[sCz * z + idx] = f2b(v);
        } else if constexpr (EPI == 5) {
          ((float*)Cv)[idx] += (mask[grow] ? v : aux[idx]);
        }
      }
    }
  }
}

__global__ __launch_bounds__(256) void fill_zero(float* p, long n) {
  const long i = (long)blockIdx.x * 256 + threadIdx.x;
  if (i < n) p[i] = 0.f;
}

extern "C" void kernel_launch(void* const* d_in, const int* in_sizes, int n_in,
                              void* d_out, int out_size, void* d_ws, size_t ws_size,
                              hipStream_t stream) {
  const int* ids = (const int*)d_in[0];
  const float* vocab_emb = (const float*)d_in[1];
  const float* audio_emb = (const float*)d_in[2];
  const float* ln_in_text = (const float*)d_in[3];
  const float* ln_in_audio = (const float*)d_in[4];
  const float* ln_post_text = (const float*)d_in[5];
  const float* ln_post_audio = (const float*)d_in[6];
  const float* wq = (const float*)d_in[7];
  const float* wk = (const float*)d_in[8];
  const float* wv = (const float*)d_in[9];
  const float* wo = (const float*)d_in[10];
  const float* wfc_t = (const float*)d_in[11];
  const float* wpj_t = (const float*)d_in[12];
  const float* wfc_a = (const float*)d_in[13];
  const float* wpj_a = (const float*)d_in[14];
  const float* ln_f = (const float*)d_in[15];

  // ---- workspace layout ----
  size_t off = 0;
  auto alloc = [&](size_t bytes) -> void* {
    void* p = (char*)d_ws + off;
    off += (bytes + 255) & ~(size_t)255;
    return p;
  };
  const size_t LW = 77594624;  // bf16 elems per layer of transposed weights
  unsigned short* wsT = (unsigned short*)alloc((size_t)2 * LW * 2);
  int* amask = (int*)alloc(S_LEN * 4);
  float* ropec = (float*)alloc((size_t)S_LEN * 64 * 4);
  float* ropes = (float*)alloc((size_t)S_LEN * 64 * 4);
  float* h = (float*)alloc((size_t)S_LEN * HID * 4);
  unsigned short* hn = (unsigned short*)alloc((size_t)S_LEN * HID * 2);
  unsigned short* hnt = (unsigned short*)alloc((size_t)S_LEN * HID * 2);
  unsigned short* hna = (unsigned short*)alloc((size_t)S_LEN * HID * 2);
  float* qkv = (float*)alloc((size_t)S_LEN * 3072 * 4);
  unsigned short* qb = (unsigned short*)alloc((size_t)S_LEN * 2048 * 2);
  unsigned short* kb = (unsigned short*)alloc((size_t)S_LEN * 512 * 2);
  unsigned short* vt = (unsigned short*)alloc((size_t)512 * S_LEN * 2);
  unsigned short* o = (unsigned short*)alloc((size_t)S_LEN * 2048 * 2);
  char* big = (char*)alloc(100663296);  // scores f32 [4][S][S] + P bf16 [4][S][S]
  float* scores = (float*)big;
  unsigned short* P = (unsigned short*)(big + 67108864);
  unsigned short* mlp_t = (unsigned short*)big;                // aliases scores (disjoint in time)
  unsigned short* mlp_a = (unsigned short*)(big + 33554432);
  float* t_out = (float*)d_out;  // text-MLP proj scratch; overwritten by final rmsnorm

  if (ws_size < off) {  // diagnostic: zero output -> absmax == max|ref| exactly
    fill_zero<<<(out_size + 255) / 256, 256, 0, stream>>>((float*)d_out, out_size);
    return;
  }

  // within-layer transposed-weight offsets (bf16 elems)
  const size_t WO_ = 6291456, WFT = 10485760, WPT = 27262976, WFA = 44040192, WPA = 60817408;

  embed_kernel<<<S_LEN, 256, 0, stream>>>(ids, vocab_emb, audio_emb, h, amask);
  rope_table<<<S_LEN * 64 / 256, 256, 0, stream>>>(ropec, ropes);

  for (int i = 0; i < 2; i++) {
    const size_t wb = (size_t)i * LW;
    transposew<<<dim3(64, 64), 256, 0, stream>>>(wq + (size_t)i * 2048 * 2048, 2048, wsT + wb, 2048, 2048);
    transposew<<<dim3(16, 64), 256, 0, stream>>>(wk + (size_t)i * 2048 * 512, 512, wsT + wb + 4194304, 2048, 512);
    transposew<<<dim3(16, 64), 256, 0, stream>>>(wv + (size_t)i * 2048 * 512, 512, wsT + wb + 5242880, 2048, 512);
    transposew<<<dim3(64, 64), 256, 0, stream>>>(wo + (size_t)i * 2048 * 2048, 2048, wsT + wb + WO_, 2048, 2048);
    transposew<<<dim3(256, 64), 256, 0, stream>>>(wfc_t + (size_t)i * 2048 * 8192, 8192, wsT + wb + WFT, 2048, 8192);
    transposew<<<dim3(64, 256), 256, 0, stream>>>(wpj_t + (size_t)i * 8192 * 2048, 2048, wsT + wb + WPT, 8192, 2048);
    transposew<<<dim3(256, 64), 256, 0, stream>>>(wfc_a + (size_t)i * 2048 * 8192, 8192, wsT + wb + WFA, 2048, 8192);
    transposew<<<dim3(64, 256), 256, 0, stream>>>(wpj_a + (size_t)i * 8192 * 2048, 2048, wsT + wb + WPA, 8192, 2048);
  }

  const float iscale = 0.08838834764831845f;  // 1/sqrt(128)
  for (int i = 0; i < 2; i++) {
    const size_t wb = (size_t)i * LW;
    rmsnorm_sel<<<S_LEN, 256, 0, stream>>>(h, amask, ln_in_text + i * HID, ln_in_audio + i * HID, hn);
    gemm_bt<0><<<dim3(24, 16, 1), 256, 0, stream>>>(hn, 2048, 0, wsT + wb, 2048, 0, qkv, 3072, 0, 2048, 1.f, nullptr, nullptr);
    rope_apply<<<dim3(S_LEN, 20), 64, 0, stream>>>(qkv, ropec, ropes, qb, kb);
    transposew<<<dim3(16, 64), 256, 0, stream>>>(qkv + 2560, 3072, vt, 2048, 512);  // v -> vt [512][S]
    for (int hc = 0; hc < 4; hc++) {  // 4 q-heads per chunk, kv head == hc
      gemm_bt<1><<<dim3(16, 16, 4), 256, 0, stream>>>(qb + hc * 512, 2048, 128, kb + hc * 128, 512, 0,
                                                      scores, 2048, (long)S_LEN * S_LEN, 128, iscale, nullptr, nullptr);
      softmax_rows<<<4 * S_LEN, 256, 0, stream>>>(scores, P);
      gemm_bt<4><<<dim3(1, 16, 4), 256, 0, stream>>>(P, 2048, (long)S_LEN * S_LEN, vt + hc * 128 * 2048, 2048, 0,
                                                     o + hc * 512, 2048, 128, 2048, 1.f, nullptr, nullptr);
    }
    gemm_bt<3><<<dim3(16, 16, 1), 256, 0, stream>>>(o, 2048, 0, wsT + wb + WO_, 2048, 0, h, 2048, 0, 2048, 1.f, nullptr, nullptr);
    rmsnorm_dual<<<S_LEN, 256, 0, stream>>>(h, ln_post_text + i * HID, ln_post_audio + i * HID, hnt, hna);
    gemm_bt<2><<<dim3(64, 16, 1), 256, 0, stream>>>(hnt, 2048, 0, wsT + wb + WFT, 2048, 0, mlp_t, 8192, 0, 2048, 1.f, nullptr, nullptr);
    gemm_bt<2><<<dim3(64, 16, 1), 256, 0, stream>>>(hna, 2048, 0, wsT + wb + WFA, 2048, 0, mlp_a, 8192, 0, 2048, 1.f, nullptr, nullptr);
    gemm_bt<0><<<dim3(16, 16, 1), 256, 0, stream>>>(mlp_t, 8192, 0, wsT + wb + WPT, 8192, 0, t_out, 2048, 0, 8192, 1.f, nullptr, nullptr);
    gemm_bt<5><<<dim3(16, 16, 1), 256, 0, stream>>>(mlp_a, 8192, 0, wsT + wb + WPA, 8192, 0, h, 2048, 0, 8192, 1.f, t_out, amask);
  }
  rmsnorm_final<<<S_LEN, 256, 0, stream>>>(h, ln_f, (float*)d_out);
}

// Round 2
// 1576.448 us; speedup vs baseline: 1.6163x; 1.6163x over previous
//
#include <hip/hip_runtime.h>
#include <hip/hip_bf16.h>
#include <math.h>

#define S_LEN 2048
#define HID   2048

typedef __bf16 bf16x8 __attribute__((ext_vector_type(8)));
typedef float  f32x4  __attribute__((ext_vector_type(4)));

__device__ __forceinline__ unsigned short f2b(float x) {
  __hip_bfloat16 h = __float2bfloat16(x);
  return __builtin_bit_cast(unsigned short, h);
}

__device__ __forceinline__ float block_sum_256(float v) {
  __shared__ float red[4];
  #pragma unroll
  for (int o = 32; o > 0; o >>= 1) v += __shfl_down(v, o, 64);
  if ((threadIdx.x & 63) == 0) red[threadIdx.x >> 6] = v;
  __syncthreads();
  v = red[0] + red[1] + red[2] + red[3];
  __syncthreads();
  return v;
}

__device__ __forceinline__ float block_max_256(float v) {
  __shared__ float redm[4];
  #pragma unroll
  for (int o = 32; o > 0; o >>= 1) v = fmaxf(v, __shfl_down(v, o, 64));
  if ((threadIdx.x & 63) == 0) redm[threadIdx.x >> 6] = v;
  __syncthreads();
  v = fmaxf(fmaxf(redm[0], redm[1]), fmaxf(redm[2], redm[3]));
  __syncthreads();
  return v;
}

// ---------------- embedding ----------------
__global__ __launch_bounds__(256) void embed_kernel(
    const int* __restrict__ ids, const float* __restrict__ vemb,
    const float* __restrict__ aemb, float* __restrict__ h, int* __restrict__ amask) {
  const int s = blockIdx.x;
  const int id = ids[s];
  const bool am = id > 31999;
  if (threadIdx.x == 0) amask[s] = am ? 1 : 0;
  const int d0 = threadIdx.x * 8;
  float out[8];
  if (am) {
    const int at = id - 32000;
    #pragma unroll
    for (int u = 0; u < 8; u++) out[u] = 0.f;
    for (int cb = 0; cb < 8; cb++) {
      const float* src = aemb + (long)(at + cb * 1024) * HID + d0;
      #pragma unroll
      for (int u = 0; u < 8; u++) out[u] += src[u];
    }
  } else {
    const float* src = vemb + (long)id * HID + d0;
    #pragma unroll
    for (int u = 0; u < 8; u++) out[u] = src[u];
  }
  float* dst = h + (long)s * HID + d0;
  #pragma unroll
  for (int u = 0; u < 8; u++) dst[u] = out[u];
}

// ---------------- weight transpose + f32->bf16 ----------------
__global__ __launch_bounds__(256) void transposew(
    const float* __restrict__ W, int ldw, unsigned short* __restrict__ Wt, int K, int N) {
  __shared__ float t[32][33];
  const int k0 = blockIdx.y * 32, n0 = blockIdx.x * 32;
  const int tx = threadIdx.x & 31, ty = threadIdx.x >> 5;
  #pragma unroll
  for (int i = 0; i < 4; i++)
    t[ty + i * 8][tx] = W[(long)(k0 + ty + i * 8) * ldw + n0 + tx];
  __syncthreads();
  #pragma unroll
  for (int i = 0; i < 4; i++)
    Wt[(long)(n0 + ty + i * 8) * K + k0 + tx] = f2b(t[tx][ty + i * 8]);
}

// ---------------- RoPE ----------------
__global__ __launch_bounds__(256) void rope_table(float* __restrict__ c, float* __restrict__ s_) {
  const int i = blockIdx.x * 256 + threadIdx.x;
  const int pos = i >> 6, j = i & 63;
  const float inv = powf(10000.f, -(float)(2 * j) * (1.f / 128.f));
  const float ang = (float)pos * inv;
  c[i] = cosf(ang);
  s_[i] = sinf(ang);
}

__global__ __launch_bounds__(64) void rope_apply(
    const float* __restrict__ qkv, const float* __restrict__ rc, const float* __restrict__ rs,
    unsigned short* __restrict__ qb, unsigned short* __restrict__ kb) {
  const int s = blockIdx.x;
  const int hh = blockIdx.y;
  const int j = threadIdx.x;
  const float c = rc[s * 64 + j], sn = rs[s * 64 + j];
  const float* base;
  unsigned short* out;
  if (hh < 16) {
    base = qkv + (long)s * 3072 + hh * 128;
    out = qb + (long)s * 2048 + hh * 128;
  } else {
    base = qkv + (long)s * 3072 + 2048 + (hh - 16) * 128;
    out = kb + (long)s * 512 + (hh - 16) * 128;
  }
  const float x1 = base[j], x2 = base[j + 64];
  out[j] = f2b(x1 * c - x2 * sn);
  out[j + 64] = f2b(x2 * c + x1 * sn);
}

// ---------------- RMSNorms ----------------
__global__ __launch_bounds__(256) void rmsnorm_sel(
    const float* __restrict__ x, const int* __restrict__ amask,
    const float* __restrict__ wt, const float* __restrict__ wa, unsigned short* __restrict__ out) {
  const long s = blockIdx.x;
  const float* xr = x + s * HID;
  const int d0 = threadIdx.x * 8;
  float v[8], ss = 0.f;
  #pragma unroll
  for (int u = 0; u < 8; u++) { v[u] = xr[d0 + u]; ss += v[u] * v[u]; }
  ss = block_sum_256(ss) * (1.f / HID);
  const float rr = rsqrtf(ss + 1e-5f);
  const float* w = amask[s] ? wa : wt;
  #pragma unroll
  for (int u = 0; u < 8; u++) out[s * HID + d0 + u] = f2b(v[u] * rr * w[d0 + u]);
}

__global__ __launch_bounds__(256) void rmsnorm_dual(
    const float* __restrict__ x, const float* __restrict__ wt, const float* __restrict__ wa,
    unsigned short* __restrict__ ot, unsigned short* __restrict__ oa) {
  const long s = blockIdx.x;
  const float* xr = x + s * HID;
  const int d0 = threadIdx.x * 8;
  float v[8], ss = 0.f;
  #pragma unroll
  for (int u = 0; u < 8; u++) { v[u] = xr[d0 + u]; ss += v[u] * v[u]; }
  ss = block_sum_256(ss) * (1.f / HID);
  const float rr = rsqrtf(ss + 1e-5f);
  #pragma unroll
  for (int u = 0; u < 8; u++) {
    const float xn = v[u] * rr;
    ot[s * HID + d0 + u] = f2b(xn * wt[d0 + u]);
    oa[s * HID + d0 + u] = f2b(xn * wa[d0 + u]);
  }
}

__global__ __launch_bounds__(256) void rmsnorm_final(
    const float* __restrict__ x, const float* __restrict__ w, float* __restrict__ out) {
  const long s = blockIdx.x;
  const float* xr = x + s * HID;
  const int d0 = threadIdx.x * 8;
  float v[8], ss = 0.f;
  #pragma unroll
  for (int u = 0; u < 8; u++) { v[u] = xr[d0 + u]; ss += v[u] * v[u]; }
  ss = block_sum_256(ss) * (1.f / HID);
  const float rr = rsqrtf(ss + 1e-5f);
  #pragma unroll
  for (int u = 0; u < 8; u++) out[s * HID + d0 + u] = v[u] * rr * w[d0 + u];
}

// ---------------- softmax (causal, row-limited loads) ----------------
__global__ __launch_bounds__(256) void softmax_rows(
    const float* __restrict__ Sc, unsigned short* __restrict__ P) {
  const long rowg = blockIdx.x;
  const int row = (int)(rowg & (S_LEN - 1));
  const float* x = Sc + rowg * S_LEN;
  unsigned short* p = P + rowg * S_LEN;
  const int d0 = threadIdx.x * 8;
  float v[8], m = -1e30f;
  if (d0 + 7 <= row) {
    #pragma unroll
    for (int u = 0; u < 8; u++) v[u] = x[d0 + u];
  } else if (d0 <= row) {
    #pragma unroll
    for (int u = 0; u < 8; u++) v[u] = (d0 + u <= row) ? x[d0 + u] : -1e30f;
  } else {
    #pragma unroll
    for (int u = 0; u < 8; u++) v[u] = -1e30f;
  }
  #pragma unroll
  for (int u = 0; u < 8; u++) m = fmaxf(m, v[u]);
  m = block_max_256(m);
  float sum = 0.f;
  #pragma unroll
  for (int u = 0; u < 8; u++) { v[u] = expf(v[u] - m); sum += v[u]; }
  sum = block_sum_256(sum);
  const float inv = 1.f / sum;
  if (d0 <= (row | 127)) {  // PV only reads k < (row|127)+1
    #pragma unroll
    for (int u = 0; u < 8; u++) p[d0 + u] = f2b(v[u] * inv);
  }
}

// ---------------- PV K-split reduce ----------------
__global__ __launch_bounds__(256) void pv_reduce(
    const float* __restrict__ part, unsigned short* __restrict__ o) {
  const int i = blockIdx.x * 256 + threadIdx.x;  // 4z*2048*128 = 1<<20
  const int z = i >> 18, s = (i >> 7) & 2047, d = i & 127;
  const float v = part[i] + part[i + (1 << 20)] + part[i + 2 * (1 << 20)] + part[i + 3 * (1 << 20)];
  o[(long)s * 2048 + z * 128 + d] = f2b(v);
}

// ---------------- 2-phase prefetch bf16 MFMA GEMM, C = A @ Bt^T ----------------
// 8 waves (512 thr), BK=64, double-buffered LDS, T2 XOR-swizzle (chunk ^= row&7).
// EPI: 0 f32 | 1 scale+causal->f32 (skip fully-masked blocks) | 2 silu->bf16
//      3 f32 += | 5 f32 += (mask?acc:aux) | 6 PV K-split partial f32
__device__ __forceinline__ void gload16(const void* g, void* l) {
  __builtin_amdgcn_global_load_lds((const __attribute__((address_space(1))) void*)g,
                                   (__attribute__((address_space(3))) void*)l, 16, 0, 0);
}

template <int BM, int BN, int EPI>
__global__ __launch_bounds__(512) void gemm2(
    const unsigned short* __restrict__ A, int lda, long sAz,
    const unsigned short* __restrict__ Bt, int ldb, long sBz,
    void* __restrict__ Cv, int ldc, long sCz, long sCx, int K, float scale,
    const float* __restrict__ aux, const int* __restrict__ mask) {
  constexpr int MF = BM / 32;   // 16-row frags per wave (wave-M = BM/2)
  constexpr int NF = BN / 64;   // 16-col frags per wave (wave-N = BN/4)
  __shared__ __align__(16) unsigned short smem[2 * (BM + BN) * 64];
  const int tid = threadIdx.x;
  const int lane = tid & 63;
  const int wave = tid >> 6;
  const int bm = blockIdx.y * BM;
  const int z = blockIdx.z;
  int bn, kbeg, nt;
  if constexpr (EPI == 6) {
    bn = 0;
    kbeg = blockIdx.x * 512;
    int keff = bm + BM; if (keff > K) keff = K;   // causal: P[q][k]==0 for k >= (q|BM-1)+1
    nt = (keff - kbeg) / 64;
    if (nt < 0) nt = 0;
    if (nt > 8) nt = 8;
  } else {
    bn = blockIdx.x * BN;
    kbeg = 0;
    nt = K / 64;
  }
  if constexpr (EPI == 1) {
    if (bn >= bm + BM) return;  // fully-masked causal block: never read downstream
  }
  A += sAz * z;
  Bt += sBz * z;
  const int wm = (wave >> 2) * (BM / 2);
  const int wn = (wave & 3) * (BN / 4);
  const int lr = lane & 15;
  const int kg = lane >> 4;
  const int swx = lr & 7;
  const int trow = tid >> 3;   // staging row (64 rows/round)
  const int tc = tid & 7;      // staging 16B chunk within 64-elem row
  // T2: LDS dest stays linear; global SOURCE pre-swizzled (chunk ^ row&7); reads swizzled.
  const long aoff = (long)(bm + trow) * lda + ((tc ^ (trow & 7)) * 8);
  const long boff = (long)(bn + trow) * ldb + ((tc ^ (trow & 7)) * 8);

  f32x4 acc[MF][NF];
  #pragma unroll
  for (int m = 0; m < MF; m++)
    #pragma unroll
    for (int n = 0; n < NF; n++) acc[m][n] = (f32x4){0.f, 0.f, 0.f, 0.f};

  auto stage = [&](int buf, int k0) {
    unsigned short* sA = &smem[(size_t)buf * (BM + BN) * 64];
    #pragma unroll
    for (int r = 0; r < BM / 64; r++)
      gload16(A + aoff + (long)r * 64 * lda + k0, sA + r * 4096 + tid * 8);
    unsigned short* sB = sA + BM * 64;
    #pragma unroll
    for (int r = 0; r < BN / 64; r++)
      gload16(Bt + boff + (long)r * 64 * ldb + k0, sB + r * 4096 + tid * 8);
  };
  auto compute = [&](int buf) {
    const unsigned short* sA = &smem[(size_t)buf * (BM + BN) * 64];
    const unsigned short* sB = sA + BM * 64;
    #pragma unroll
    for (int ks = 0; ks < 2; ks++) {
      bf16x8 af[MF], bv[NF];
      #pragma unroll
      for (int m = 0; m < MF; m++) {
        const int row = wm + m * 16 + lr;
        af[m] = *(const bf16x8*)(sA + row * 64 + (((ks * 4 + kg) ^ swx) * 8));
      }
      #pragma unroll
      for (int n = 0; n < NF; n++) {
        const int row = wn + n * 16 + lr;
        bv[n] = *(const bf16x8*)(sB + row * 64 + (((ks * 4 + kg) ^ swx) * 8));
      }
      #pragma unroll
      for (int m = 0; m < MF; m++)
        #pragma unroll
        for (int n = 0; n < NF; n++)
          acc[m][n] = __builtin_amdgcn_mfma_f32_16x16x32_bf16(af[m], bv[n], acc[m][n], 0, 0, 0);
    }
  };

  if (nt > 0) {
    stage(0, kbeg);
    asm volatile("s_waitcnt vmcnt(0)" ::: "memory");
    __syncthreads();
    int cur = 0;
    for (int t = 0; t < nt; t++) {
      if (t + 1 < nt) stage(cur ^ 1, kbeg + (t + 1) * 64);
      compute(cur);
      asm volatile("s_waitcnt vmcnt(0)" ::: "memory");
      __syncthreads();
      cur ^= 1;
    }
  }

  #pragma unroll
  for (int m = 0; m < MF; m++) {
    #pragma unroll
    for (int n = 0; n < NF; n++) {
      #pragma unroll
      for (int r = 0; r < 4; r++) {
        const int grow = bm + wm + m * 16 + kg * 4 + r;
        const int gcol = bn + wn + n * 16 + lr;
        const long idx = (long)grow * ldc + gcol;
        float v = acc[m][n][r];
        if constexpr (EPI == 0) {
          ((float*)Cv)[sCz * z + idx] = v;
        } else if constexpr (EPI == 1) {
          v *= scale;
          if (gcol > grow) v = -1e9f;
          ((float*)Cv)[sCz * z + idx] = v;
        } else if constexpr (EPI == 2) {
          ((unsigned short*)Cv)[idx] = f2b(v / (1.f + expf(-v)));
        } else if constexpr (EPI == 3) {
          ((float*)Cv)[idx] += v;
        } else if constexpr (EPI == 5) {
          ((float*)Cv)[idx] += (mask[grow] ? v : aux[idx]);
        } else if constexpr (EPI == 6) {
          ((float*)Cv)[(long)blockIdx.x * sCx + sCz * z + idx] = v;
        }
      }
    }
  }
}

__global__ __launch_bounds__(256) void fill_zero(float* p, long n) {
  const long i = (long)blockIdx.x * 256 + threadIdx.x;
  if (i < n) p[i] = 0.f;
}

extern "C" void kernel_launch(void* const* d_in, const int* in_sizes, int n_in,
                              void* d_out, int out_size, void* d_ws, size_t ws_size,
                              hipStream_t stream) {
  const int* ids = (const int*)d_in[0];
  const float* vocab_emb = (const float*)d_in[1];
  const float* audio_emb = (const float*)d_in[2];
  const float* ln_in_text = (const float*)d_in[3];
  const float* ln_in_audio = (const float*)d_in[4];
  const float* ln_post_text = (const float*)d_in[5];
  const float* ln_post_audio = (const float*)d_in[6];
  const float* wq = (const float*)d_in[7];
  const float* wk = (const float*)d_in[8];
  const float* wv = (const float*)d_in[9];
  const float* wo = (const float*)d_in[10];
  const float* wfc_t = (const float*)d_in[11];
  const float* wpj_t = (const float*)d_in[12];
  const float* wfc_a = (const float*)d_in[13];
  const float* wpj_a = (const float*)d_in[14];
  const float* ln_f = (const float*)d_in[15];

  size_t off = 0;
  auto alloc = [&](size_t bytes) -> void* {
    void* p = (char*)d_ws + off;
    off += (bytes + 255) & ~(size_t)255;
    return p;
  };
  const size_t LW = 77594624;
  unsigned short* wsT = (unsigned short*)alloc((size_t)2 * LW * 2);
  int* amask = (int*)alloc(S_LEN * 4);
  float* ropec = (float*)alloc((size_t)S_LEN * 64 * 4);
  float* ropes = (float*)alloc((size_t)S_LEN * 64 * 4);
  float* h = (float*)alloc((size_t)S_LEN * HID * 4);
  unsigned short* hn = (unsigned short*)alloc((size_t)S_LEN * HID * 2);
  unsigned short* hnt = (unsigned short*)alloc((size_t)S_LEN * HID * 2);
  unsigned short* hna = (unsigned short*)alloc((size_t)S_LEN * HID * 2);
  float* qkv = (float*)alloc((size_t)S_LEN * 3072 * 4);
  unsigned short* qb = (unsigned short*)alloc((size_t)S_LEN * 2048 * 2);
  unsigned short* kb = (unsigned short*)alloc((size_t)S_LEN * 512 * 2);
  unsigned short* vt = (unsigned short*)alloc((size_t)512 * S_LEN * 2);
  unsigned short* o = (unsigned short*)alloc((size_t)S_LEN * 2048 * 2);
  char* big = (char*)alloc(100663296);
  float* scores = (float*)big;                     // [4][S][S] f32
  unsigned short* P = (unsigned short*)(big + 67108864);  // [4][S][S] bf16
  float* partial = (float*)big;                    // PV partials alias scores (disjoint in time)
  unsigned short* mlp_t = (unsigned short*)big;
  unsigned short* mlp_a = (unsigned short*)(big + 33554432);
  float* t_out = (float*)d_out;

  if (ws_size < off) {
    fill_zero<<<(out_size + 255) / 256, 256, 0, stream>>>((float*)d_out, out_size);
    return;
  }

  const size_t WO_ = 6291456, WFT = 10485760, WPT = 27262976, WFA = 44040192, WPA = 60817408;

  embed_kernel<<<S_LEN, 256, 0, stream>>>(ids, vocab_emb, audio_emb, h, amask);
  rope_table<<<S_LEN * 64 / 256, 256, 0, stream>>>(ropec, ropes);

  for (int i = 0; i < 2; i++) {
    const size_t wb = (size_t)i * LW;
    transposew<<<dim3(64, 64), 256, 0, stream>>>(wq + (size_t)i * 2048 * 2048, 2048, wsT + wb, 2048, 2048);
    transposew<<<dim3(16, 64), 256, 0, stream>>>(wk + (size_t)i * 2048 * 512, 512, wsT + wb + 4194304, 2048, 512);
    transposew<<<dim3(16, 64), 256, 0, stream>>>(wv + (size_t)i * 2048 * 512, 512, wsT + wb + 5242880, 2048, 512);
    transposew<<<dim3(64, 64), 256, 0, stream>>>(wo + (size_t)i * 2048 * 2048, 2048, wsT + wb + WO_, 2048, 2048);
    transposew<<<dim3(256, 64), 256, 0, stream>>>(wfc_t + (size_t)i * 2048 * 8192, 8192, wsT + wb + WFT, 2048, 8192);
    transposew<<<dim3(64, 256), 256, 0, stream>>>(wpj_t + (size_t)i * 8192 * 2048, 2048, wsT + wb + WPT, 8192, 2048);
    transposew<<<dim3(256, 64), 256, 0, stream>>>(wfc_a + (size_t)i * 2048 * 8192, 8192, wsT + wb + WFA, 2048, 8192);
    transposew<<<dim3(64, 256), 256, 0, stream>>>(wpj_a + (size_t)i * 8192 * 2048, 2048, wsT + wb + WPA, 8192, 2048);
  }

  const float iscale = 0.08838834764831845f;  // 1/sqrt(128)
  for (int i = 0; i < 2; i++) {
    const size_t wb = (size_t)i * LW;
    rmsnorm_sel<<<S_LEN, 256, 0, stream>>>(h, amask, ln_in_text + i * HID, ln_in_audio + i * HID, hn);
    gemm2<128, 128, 0><<<dim3(24, 16, 1), 512, 0, stream>>>(hn, 2048, 0, wsT + wb, 2048, 0,
        qkv, 3072, 0, 0, 2048, 1.f, nullptr, nullptr);
    rope_apply<<<dim3(S_LEN, 20), 64, 0, stream>>>(qkv, ropec, ropes, qb, kb);
    transposew<<<dim3(16, 64), 256, 0, stream>>>(qkv + 2560, 3072, vt, 2048, 512);
    for (int hc = 0; hc < 4; hc++) {
      gemm2<256, 256, 1><<<dim3(8, 8, 4), 512, 0, stream>>>(qb + hc * 512, 2048, 128, kb + hc * 128, 512, 0,
          scores, 2048, (long)S_LEN * S_LEN, 0, 128, iscale, nullptr, nullptr);
      softmax_rows<<<4 * S_LEN, 256, 0, stream>>>(scores, P);
      gemm2<128, 128, 6><<<dim3(4, 16, 4), 512, 0, stream>>>(P, 2048, (long)S_LEN * S_LEN, vt + (size_t)hc * 128 * 2048, 2048, 0,
          partial, 128, (long)1 << 18, (long)1 << 20, 2048, 1.f, nullptr, nullptr);
      pv_reduce<<<4096, 256, 0, stream>>>(partial, o + hc * 512);
    }
    gemm2<128, 128, 3><<<dim3(16, 16, 1), 512, 0, stream>>>(o, 2048, 0, wsT + wb + WO_, 2048, 0,
        h, 2048, 0, 0, 2048, 1.f, nullptr, nullptr);
    rmsnorm_dual<<<S_LEN, 256, 0, stream>>>(h, ln_post_text + i * HID, ln_post_audio + i * HID, hnt, hna);
    gemm2<256, 256, 2><<<dim3(32, 8, 1), 512, 0, stream>>>(hnt, 2048, 0, wsT + wb + WFT, 2048, 0,
        mlp_t, 8192, 0, 0, 2048, 1.f, nullptr, nullptr);
    gemm2<256, 256, 2><<<dim3(32, 8, 1), 512, 0, stream>>>(hna, 2048, 0, wsT + wb + WFA, 2048, 0,
        mlp_a, 8192, 0, 0, 2048, 1.f, nullptr, nullptr);
    gemm2<128, 128, 0><<<dim3(16, 16, 1), 512, 0, stream>>>(mlp_t, 8192, 0, wsT + wb + WPT, 8192, 0,
        t_out, 2048, 0, 0, 8192, 1.f, nullptr, nullptr);
    gemm2<128, 128, 5><<<dim3(16, 16, 1), 512, 0, stream>>>(mlp_a, 8192, 0, wsT + wb + WPA, 8192, 0,
        h, 2048, 0, 0, 8192, 1.f, t_out, amask);
  }
  rmsnorm_final<<<S_LEN, 256, 0, stream>>>(h, ln_f, (float*)d_out);
}